// Round 2
// baseline (1441.428 us; speedup 1.0000x reference)
//
#include <hip/hip_runtime.h>

typedef unsigned int uint32;
typedef unsigned short ushort16;

// Problem constants
constexpr int CN0 = 100000;
constexpr int CN1 = 150000;
constexpr int CN2 = 80000;
constexpr int CNE = 1000000;
constexpr int CD  = 128;
constexpr int NBINS = 3 * CN0;                     // 300000 rows across 3 adjacencies
constexpr int SCAN_BLOCKS = (NBINS + 1023) / 1024; // 293

constexpr size_t align256(size_t x) { return (x + 255) & ~(size_t)255; }

// ---------------- workspace layout (bytes) — peak ~179 MB ----------------
constexpr size_t OFF_H0   = 0;                                        // CN0*CD f32
constexpr size_t OFF_H1B  = align256(OFF_H0 + (size_t)CN0 * CD * 4);  // CN1*CD bf16
constexpr size_t OFF_H2B  = align256(OFF_H1B + (size_t)CN1 * CD * 2); // CN2*CD bf16
constexpr size_t OFF_AGG  = align256(OFF_H2B + (size_t)CN2 * CD * 2); // CN0*CD f32, reused 3x
constexpr size_t OFF_A1   = align256(OFF_AGG + (size_t)CN0 * CD * 4);
constexpr size_t OFF_A2   = align256(OFF_A1 + (size_t)CN0 * 4);
constexpr size_t OFF_HIST = align256(OFF_A2 + (size_t)(CN0 + CN1 + CN2) * 4);
constexpr size_t OFF_RS   = align256(OFF_HIST + (size_t)NBINS * 4);
constexpr size_t OFF_CUR  = align256(OFF_RS + (size_t)(NBINS + 1) * 4);
constexpr size_t OFF_SC   = align256(OFF_CUR + (size_t)NBINS * 4);
constexpr size_t OFF_BS   = align256(OFF_SC + (size_t)3 * CNE * 4);
constexpr size_t OFF_END  = OFF_BS + (size_t)SCAN_BLOCKS * 4;

// ---------------- bf16 helpers ----------------
__device__ inline float b2f(ushort16 u) {
  union { uint32 i; float f; } v; v.i = ((uint32)u) << 16; return v.f;
}
__device__ inline ushort16 f2b(float f) {
  union { float f; uint32 i; } v; v.f = f;
  uint32 r = (v.i + 0x7FFFu + ((v.i >> 16) & 1u)) >> 16;
  return (ushort16)r;
}
__device__ inline uint32 pack2(float a, float b) {
  return (uint32)f2b(a) | ((uint32)f2b(b) << 16);
}
__device__ inline float2 load2(const float* p, size_t i) { return *(const float2*)(p + i); }
__device__ inline float2 load2(const ushort16* p, size_t i) {
  uint32 u = *(const uint32*)(p + i);
  union { uint32 i; float f; } lo, hi;
  lo.i = u << 16; hi.i = u & 0xFFFF0000u;
  return make_float2(lo.f, hi.f);
}
__device__ inline float loadv(const float* p, size_t i) { return p[i]; }
__device__ inline float loadv(const ushort16* p, size_t i) { return b2f(p[i]); }

// ---------------- tiled fp32-accumulate GEMM: C[M x 128] (+)= A[M x 128] @ W + bias ----
// TA/TC in {float, ushort16(bf16)}. INIT=false: accumulate into fp32 C (read-add-write).
template <bool RELU, bool INIT, bool BIAS, typename TA, typename TC>
__global__ __launch_bounds__(256) void gemm_kernel(
    const TA* __restrict__ A, const float* __restrict__ W,
    const float* __restrict__ bias, TC* __restrict__ C, int M) {
  __shared__ float As[32][66];   // [k][m], pad 66 -> 2-way alias (free on gfx950)
  __shared__ float Ws[32][128];  // [k][n]
  const int t = threadIdx.x;
  const int tn = t & 15;         // 16 col-groups of 8
  const int tm = t >> 4;         // 16 row-groups of 4
  const int row0 = blockIdx.x * 64;
  const int kl = t & 31, rb = t >> 5;   // A staging: 8 rows/pass
  const int nl = t & 127, kw = t >> 7;  // W staging: 2 k/pass

  float acc[4][8];
#pragma unroll
  for (int i = 0; i < 4; ++i)
#pragma unroll
    for (int j = 0; j < 8; ++j) acc[i][j] = 0.f;

  for (int kc = 0; kc < CD; kc += 32) {
#pragma unroll
    for (int p = 0; p < 8; ++p) {
      int r = rb + p * 8;
      int grow = row0 + r;
      float v = (grow < M) ? loadv(A, (size_t)grow * CD + kc + kl) : 0.f;
      As[kl][r] = v;
    }
#pragma unroll
    for (int p = 0; p < 16; ++p) {
      int k = kw + p * 2;
      Ws[k][nl] = W[(size_t)(kc + k) * CD + nl];
    }
    __syncthreads();
#pragma unroll 8
    for (int k = 0; k < 32; ++k) {
      const float2 a01 = *(const float2*)&As[k][tm * 4];
      const float2 a23 = *(const float2*)&As[k][tm * 4 + 2];
      const float4 w0 = *(const float4*)&Ws[k][tn * 8];
      const float4 w1 = *(const float4*)&Ws[k][tn * 8 + 4];
      const float av[4] = {a01.x, a01.y, a23.x, a23.y};
      const float wv[8] = {w0.x, w0.y, w0.z, w0.w, w1.x, w1.y, w1.z, w1.w};
#pragma unroll
      for (int i = 0; i < 4; ++i)
#pragma unroll
        for (int j = 0; j < 8; ++j) acc[i][j] = fmaf(av[i], wv[j], acc[i][j]);
    }
    __syncthreads();
  }

  float bv[8];
  if constexpr (BIAS) {
    const float4 b0 = *(const float4*)&bias[tn * 8];
    const float4 b1 = *(const float4*)&bias[tn * 8 + 4];
    bv[0] = b0.x; bv[1] = b0.y; bv[2] = b0.z; bv[3] = b0.w;
    bv[4] = b1.x; bv[5] = b1.y; bv[6] = b1.z; bv[7] = b1.w;
  }
#pragma unroll
  for (int i = 0; i < 4; ++i) {
    int grow = row0 + tm * 4 + i;
    if (grow < M) {
      float o[8];
#pragma unroll
      for (int j = 0; j < 8; ++j) {
        float v = acc[i][j];
        if constexpr (BIAS) v += bv[j];
        o[j] = RELU ? fmaxf(v, 0.f) : v;
      }
      if constexpr (INIT) {
        if constexpr (sizeof(TC) == 2) {
          uint4 pk;
          pk.x = pack2(o[0], o[1]); pk.y = pack2(o[2], o[3]);
          pk.z = pack2(o[4], o[5]); pk.w = pack2(o[6], o[7]);
          *(uint4*)((ushort16*)C + (size_t)grow * CD + tn * 8) = pk;
        } else {
          *(float4*)((float*)C + (size_t)grow * CD + tn * 8) = make_float4(o[0], o[1], o[2], o[3]);
          *(float4*)((float*)C + (size_t)grow * CD + tn * 8 + 4) = make_float4(o[4], o[5], o[6], o[7]);
        }
      } else {
        float* cp = (float*)C + (size_t)grow * CD + tn * 8;
        float4 c0 = *(float4*)cp;
        float4 c1 = *(float4*)(cp + 4);
        *(float4*)cp = make_float4(o[0] + c0.x, o[1] + c0.y, o[2] + c0.z, o[3] + c0.w);
        *(float4*)(cp + 4) = make_float4(o[4] + c1.x, o[5] + c1.y, o[6] + c1.z, o[7] + c1.w);
      }
    }
  }
}

// ---------------- per-row dots with a1_w / a2_w (one wave per row) ----------------
template <typename TH>
__global__ void adot_kernel(const TH* __restrict__ H, int M,
                            const float* __restrict__ a1w, const float* __restrict__ a1b,
                            float* __restrict__ a1out,
                            const float* __restrict__ a2w, const float* __restrict__ a2b,
                            float* __restrict__ a2out) {
  int w = (blockIdx.x * blockDim.x + threadIdx.x) >> 6;
  int lane = threadIdx.x & 63;
  if (w >= M) return;
  float2 h = load2(H, (size_t)w * CD + lane * 2);
  float2 w2 = *(const float2*)(a2w + lane * 2);
  float s2 = h.x * w2.x + h.y * w2.y;
  float s1 = 0.f;
  if (a1out) {
    float2 w1 = *(const float2*)(a1w + lane * 2);
    s1 = h.x * w1.x + h.y * w1.y;
  }
#pragma unroll
  for (int off = 32; off > 0; off >>= 1) {
    s2 += __shfl_down(s2, off, 64);
    s1 += __shfl_down(s1, off, 64);
  }
  if (lane == 0) {
    a2out[w] = s2 + a2b[0];
    if (a1out) a1out[w] = s1 + a1b[0];
  }
}

// ---------------- counting sort of edges by destination row ----------------
__global__ void zero_kernel(int* __restrict__ p, int n) {
  int i = blockIdx.x * 256 + threadIdx.x;
  if (i < n) p[i] = 0;
}

__global__ void hist_kernel(const int* __restrict__ r0, const int* __restrict__ r1,
                            const int* __restrict__ r2, int* __restrict__ hist) {
  int e = blockIdx.x * 256 + threadIdx.x;
  if (e < CNE) atomicAdd(&hist[r0[e]], 1);
  else if (e < 2 * CNE) atomicAdd(&hist[CN0 + r1[e - CNE]], 1);
  else if (e < 3 * CNE) atomicAdd(&hist[2 * CN0 + r2[e - 2 * CNE]], 1);
}

__global__ void scan1_kernel(const int* __restrict__ hist, int* __restrict__ rs,
                             int* __restrict__ bsums) {
  __shared__ int lds[256];
  int t = threadIdx.x;
  int idx0 = blockIdx.x * 1024 + t * 4;
  int v[4];
#pragma unroll
  for (int j = 0; j < 4; ++j) v[j] = (idx0 + j < NBINS) ? hist[idx0 + j] : 0;
  int tsum = v[0] + v[1] + v[2] + v[3];
  lds[t] = tsum;
  __syncthreads();
  for (int off = 1; off < 256; off <<= 1) {
    int x = (t >= off) ? lds[t - off] : 0;
    __syncthreads();
    lds[t] += x;
    __syncthreads();
  }
  int run = lds[t] - tsum;  // exclusive prefix within block
  if (t == 255) bsums[blockIdx.x] = lds[255];
#pragma unroll
  for (int j = 0; j < 4; ++j) {
    if (idx0 + j < NBINS) rs[idx0 + j] = run;
    run += v[j];
  }
}

__global__ void scan2_kernel(int* __restrict__ bsums, int nb) {
  __shared__ int lds[512];
  int t = threadIdx.x;
  int v = (t < nb) ? bsums[t] : 0;
  lds[t] = v;
  __syncthreads();
  for (int off = 1; off < 512; off <<= 1) {
    int x = (t >= off) ? lds[t - off] : 0;
    __syncthreads();
    lds[t] += x;
    __syncthreads();
  }
  if (t < nb) bsums[t] = lds[t] - v;  // exclusive
}

__global__ void scan3_kernel(int* __restrict__ rs, int* __restrict__ cur,
                             const int* __restrict__ bsums) {
  int t = threadIdx.x;
  int idx0 = blockIdx.x * 1024 + t * 4;
  int off = bsums[blockIdx.x];
#pragma unroll
  for (int j = 0; j < 4; ++j) {
    int idx = idx0 + j;
    if (idx < NBINS) {
      int val = rs[idx] + off;
      rs[idx] = val;
      cur[idx] = val;
    }
  }
  if (blockIdx.x == 0 && t == 0) rs[NBINS] = 3 * CNE;
}

__global__ void scatter_kernel(const int* __restrict__ r0, const int* __restrict__ c0,
                               const int* __restrict__ r1, const int* __restrict__ c1,
                               const int* __restrict__ r2, const int* __restrict__ c2,
                               int* __restrict__ cur, int* __restrict__ scols) {
  int e = blockIdx.x * 256 + threadIdx.x;
  if (e >= 3 * CNE) return;
  int row, col, base;
  if (e < CNE) { row = r0[e]; col = c0[e]; base = 0; }
  else if (e < 2 * CNE) { row = r1[e - CNE]; col = c1[e - CNE]; base = CN0; }
  else { row = r2[e - 2 * CNE]; col = c2[e - 2 * CNE]; base = 2 * CN0; }
  int pos = atomicAdd(&cur[base + row], 1);
  scols[pos] = col;
}

// ---------------- attention aggregation: one wave per row of one adjacency ----------
// rs_base = rs + a*CN0 (global binning); writes fp32 agg panel [CN0 x 128].
template <typename TX>
__global__ void agg_kernel(const int* __restrict__ rs_base, const int* __restrict__ scols,
                           const TX* __restrict__ xj, const float* __restrict__ a1_0,
                           const float* __restrict__ a2, float* __restrict__ aggout) {
  int w = (blockIdx.x * blockDim.x + threadIdx.x) >> 6;
  if (w >= CN0) return;
  int lane = threadIdx.x & 63;
  int s = rs_base[w], e = rs_base[w + 1];
  float a1v = a1_0[w];
  float accx = 0.f, accy = 0.f;
  for (int p = s; p < e; ++p) {
    int col = scols[p];
    float z = a1v + a2[col];
    float att = 1.0f / (1.0f + __expf(-z));
    float2 xv = load2(xj, (size_t)col * CD + lane * 2);
    accx = fmaf(att, xv.x, accx);
    accy = fmaf(att, xv.y, accy);
  }
  *(float2*)(aggout + (size_t)w * CD + lane * 2) = make_float2(accx, accy);
}

// ---------------- launch ----------------
extern "C" void kernel_launch(void* const* d_in, const int* in_sizes, int n_in,
                              void* d_out, int out_size, void* d_ws, size_t ws_size,
                              hipStream_t stream) {
  const float* x0 = (const float*)d_in[0];
  const float* x1 = (const float*)d_in[1];
  const float* x2 = (const float*)d_in[2];
  const float* W1 = (const float*)d_in[3];
  const float* b1 = (const float*)d_in[4];
  const float* a1_w = (const float*)d_in[5];
  const float* a1_b = (const float*)d_in[6];
  const float* a2_w = (const float*)d_in[7];
  const float* a2_b = (const float*)d_in[8];
  const float* Wagg = (const float*)d_in[9];
  const float* bagg = (const float*)d_in[10];
  const int* adj0_r = (const int*)d_in[11];
  const int* adj0_c = (const int*)d_in[12];
  const int* adj1_r = (const int*)d_in[13];
  const int* adj1_c = (const int*)d_in[14];
  const int* adj2_r = (const int*)d_in[15];
  const int* adj2_c = (const int*)d_in[16];
  float* out = (float*)d_out;

  // Tripwire: if workspace is too small, bail cleanly (bench shows absmax fail,
  // not a crash) so we can distinguish ws overflow from a kernel fault.
  if (ws_size < OFF_END) return;

  char* ws = (char*)d_ws;
  float*    h0     = (float*)(ws + OFF_H0);
  ushort16* h1b    = (ushort16*)(ws + OFF_H1B);
  ushort16* h2b    = (ushort16*)(ws + OFF_H2B);
  float*    aggbuf = (float*)(ws + OFF_AGG);
  float*    a1_0   = (float*)(ws + OFF_A1);
  float*    a2all  = (float*)(ws + OFF_A2);
  int*      hist   = (int*)(ws + OFF_HIST);
  int*      rs     = (int*)(ws + OFF_RS);
  int*      cur    = (int*)(ws + OFF_CUR);
  int*      scols  = (int*)(ws + OFF_SC);
  int*      bsums  = (int*)(ws + OFF_BS);

  // 1) lin1: h = relu(x @ W1 + b1); h0 fp32, h1/h2 bf16
  gemm_kernel<true, true, true, float, float>
      <<<(CN0 + 63) / 64, 256, 0, stream>>>(x0, W1, b1, h0, CN0);
  gemm_kernel<true, true, true, float, ushort16>
      <<<(CN1 + 63) / 64, 256, 0, stream>>>(x1, W1, b1, h1b, CN1);
  gemm_kernel<true, true, true, float, ushort16>
      <<<(CN2 + 63) / 64, 256, 0, stream>>>(x2, W1, b1, h2b, CN2);

  // 2) attention scalars
  adot_kernel<float><<<(CN0 * 64 + 255) / 256, 256, 0, stream>>>(
      h0, CN0, a1_w, a1_b, a1_0, a2_w, a2_b, a2all);
  adot_kernel<ushort16><<<(CN1 * 64 + 255) / 256, 256, 0, stream>>>(
      h1b, CN1, nullptr, nullptr, nullptr, a2_w, a2_b, a2all + CN0);
  adot_kernel<ushort16><<<(CN2 * 64 + 255) / 256, 256, 0, stream>>>(
      h2b, CN2, nullptr, nullptr, nullptr, a2_w, a2_b, a2all + CN0 + CN1);

  // 3) counting sort of all 3 edge lists by destination row
  zero_kernel<<<(NBINS + 255) / 256, 256, 0, stream>>>(hist, NBINS);
  hist_kernel<<<(3 * CNE + 255) / 256, 256, 0, stream>>>(adj0_r, adj1_r, adj2_r, hist);
  scan1_kernel<<<SCAN_BLOCKS, 256, 0, stream>>>(hist, rs, bsums);
  scan2_kernel<<<1, 512, 0, stream>>>(bsums, SCAN_BLOCKS);
  scan3_kernel<<<SCAN_BLOCKS, 256, 0, stream>>>(rs, cur, bsums);
  scatter_kernel<<<(3 * CNE + 255) / 256, 256, 0, stream>>>(
      adj0_r, adj0_c, adj1_r, adj1_c, adj2_r, adj2_c, cur, scols);

  // 4) out = h0 @ Wagg[0:128] + bagg
  gemm_kernel<false, true, true, float, float>
      <<<(CN0 + 63) / 64, 256, 0, stream>>>(h0, Wagg, bagg, out, CN0);

  // 5) per adjacency: agg into aggbuf, then out += aggbuf @ Wagg panel
  agg_kernel<float><<<(CN0 * 64 + 255) / 256, 256, 0, stream>>>(
      rs, scols, h0, a1_0, a2all, aggbuf);
  gemm_kernel<false, false, false, float, float>
      <<<(CN0 + 63) / 64, 256, 0, stream>>>(aggbuf, Wagg + 1 * CD * CD, nullptr, out, CN0);

  agg_kernel<ushort16><<<(CN0 * 64 + 255) / 256, 256, 0, stream>>>(
      rs + CN0, scols, h1b, a1_0, a2all + CN0, aggbuf);
  gemm_kernel<false, false, false, float, float>
      <<<(CN0 + 63) / 64, 256, 0, stream>>>(aggbuf, Wagg + 2 * CD * CD, nullptr, out, CN0);

  agg_kernel<ushort16><<<(CN0 * 64 + 255) / 256, 256, 0, stream>>>(
      rs + 2 * CN0, scols, h2b, a1_0, a2all + CN0 + CN1, aggbuf);
  gemm_kernel<false, false, false, float, float>
      <<<(CN0 + 63) / 64, 256, 0, stream>>>(aggbuf, Wagg + 3 * CD * CD, nullptr, out, CN0);
}

// Round 3
// 1128.023 us; speedup vs baseline: 1.2778x; 1.2778x over previous
//
#include <hip/hip_runtime.h>

typedef unsigned int uint32;
typedef unsigned short ushort16;

// Problem constants
constexpr int CN0 = 100000;
constexpr int CN1 = 150000;
constexpr int CN2 = 80000;
constexpr int CNE = 1000000;
constexpr int CD  = 128;
constexpr int NBINS = 3 * CN0;                  // 300000 rows across 3 adjacencies
constexpr int TOT_E = 3 * CNE;

// two-level sort params
constexpr int NB    = (NBINS + 511) / 512;      // 586 coarse buckets (bin>>9)
constexpr int CHUNK = 8192;                     // edges per block in hist/reorder
constexpr int G     = (TOT_E + CHUNK - 1) / CHUNK;  // 367 blocks
constexpr int NBG   = NB * G;                   // 215062 (bucket-major block hist)
constexpr int CSCAN_BLOCKS = (NBG + 1023) / 1024;   // 211

constexpr size_t align256(size_t x) { return (x + 255) & ~(size_t)255; }

// ---------------- workspace layout (bytes) — peak ~137 MB ----------------
constexpr size_t OFF_H0B = 0;                                          // CN0*CD bf16
constexpr size_t OFF_H1B = align256(OFF_H0B + (size_t)CN0 * CD * 2);   // CN1*CD bf16
constexpr size_t OFF_H2B = align256(OFF_H1B + (size_t)CN1 * CD * 2);   // CN2*CD bf16
constexpr size_t OFF_AGG = align256(OFF_H2B + (size_t)CN2 * CD * 2);   // CN0*CD bf16 (reused 3x)
constexpr size_t OFF_A1  = align256(OFF_AGG + (size_t)CN0 * CD * 2);
constexpr size_t OFF_A2  = align256(OFF_A1 + (size_t)CN0 * 4);
constexpr size_t OFF_RS  = align256(OFF_A2 + (size_t)(CN0 + CN1 + CN2) * 4); // NBINS+1 ints
constexpr size_t OFF_BH  = align256(OFF_RS + (size_t)(NBINS + 1) * 4);       // NBG ints
constexpr size_t OFF_BB  = align256(OFF_BH + (size_t)NBG * 4);               // TOT_E uint32
constexpr size_t OFF_SCL = align256(OFF_BB + (size_t)TOT_E * 4);             // TOT_E int
constexpr size_t OFF_BS  = align256(OFF_SCL + (size_t)TOT_E * 4);            // scan block sums
constexpr size_t OFF_END = OFF_BS + (size_t)CSCAN_BLOCKS * 4;

// ---------------- bf16 helpers ----------------
__device__ inline float b2f(ushort16 u) {
  union { uint32 i; float f; } v; v.i = ((uint32)u) << 16; return v.f;
}
__device__ inline ushort16 f2b(float f) {
  union { float f; uint32 i; } v; v.f = f;
  uint32 r = (v.i + 0x7FFFu + ((v.i >> 16) & 1u)) >> 16;
  return (ushort16)r;
}
__device__ inline uint32 pack2(float a, float b) {
  return (uint32)f2b(a) | ((uint32)f2b(b) << 16);
}
__device__ inline float2 load2(const float* p, size_t i) { return *(const float2*)(p + i); }
__device__ inline float2 load2(const ushort16* p, size_t i) {
  uint32 u = *(const uint32*)(p + i);
  union { uint32 i; float f; } lo, hi;
  lo.i = u << 16; hi.i = u & 0xFFFF0000u;
  return make_float2(lo.f, hi.f);
}
__device__ inline float loadv(const float* p, size_t i) { return p[i]; }
__device__ inline float loadv(const ushort16* p, size_t i) { return b2f(p[i]); }

// ---------------- tiled fp32-accumulate GEMM: C[M x 128] (+)= A[M x 128] @ W + bias ----
template <bool RELU, bool INIT, bool BIAS, typename TA, typename TC>
__global__ __launch_bounds__(256) void gemm_kernel(
    const TA* __restrict__ A, const float* __restrict__ W,
    const float* __restrict__ bias, TC* __restrict__ C, int M) {
  __shared__ float As[32][66];   // [k][m], pad 66 -> 2-way alias (free on gfx950)
  __shared__ float Ws[32][128];  // [k][n]
  const int t = threadIdx.x;
  const int tn = t & 15;         // 16 col-groups of 8
  const int tm = t >> 4;         // 16 row-groups of 4
  const int row0 = blockIdx.x * 64;

  float acc[4][8];
#pragma unroll
  for (int i = 0; i < 4; ++i)
#pragma unroll
    for (int j = 0; j < 8; ++j) acc[i][j] = 0.f;

  for (int kc = 0; kc < CD; kc += 32) {
    if constexpr (sizeof(TA) == 2) {
      // bf16 A: uint32 (2-elem) loads; 16 k-pairs x 16 rows per pass, 4 passes
      const int k2 = (t & 15) * 2, r2 = t >> 4;
#pragma unroll
      for (int p = 0; p < 4; ++p) {
        int r = r2 + p * 16;
        int grow = row0 + r;
        float2 v = (grow < M) ? load2((const ushort16*)A, (size_t)grow * CD + kc + k2)
                              : make_float2(0.f, 0.f);
        As[k2][r] = v.x;
        As[k2 + 1][r] = v.y;
      }
    } else {
      const int kl = t & 31, rb = t >> 5;  // 8 rows/pass
#pragma unroll
      for (int p = 0; p < 8; ++p) {
        int r = rb + p * 8;
        int grow = row0 + r;
        float v = (grow < M) ? loadv(A, (size_t)grow * CD + kc + kl) : 0.f;
        As[kl][r] = v;
      }
    }
    {
      const int nl = t & 127, kw = t >> 7;  // W staging: 2 k/pass
#pragma unroll
      for (int p = 0; p < 16; ++p) {
        int k = kw + p * 2;
        Ws[k][nl] = W[(size_t)(kc + k) * CD + nl];
      }
    }
    __syncthreads();
#pragma unroll 8
    for (int k = 0; k < 32; ++k) {
      const float2 a01 = *(const float2*)&As[k][tm * 4];
      const float2 a23 = *(const float2*)&As[k][tm * 4 + 2];
      const float4 w0 = *(const float4*)&Ws[k][tn * 8];
      const float4 w1 = *(const float4*)&Ws[k][tn * 8 + 4];
      const float av[4] = {a01.x, a01.y, a23.x, a23.y};
      const float wv[8] = {w0.x, w0.y, w0.z, w0.w, w1.x, w1.y, w1.z, w1.w};
#pragma unroll
      for (int i = 0; i < 4; ++i)
#pragma unroll
        for (int j = 0; j < 8; ++j) acc[i][j] = fmaf(av[i], wv[j], acc[i][j]);
    }
    __syncthreads();
  }

  float bv[8];
  if constexpr (BIAS) {
    const float4 b0 = *(const float4*)&bias[tn * 8];
    const float4 b1 = *(const float4*)&bias[tn * 8 + 4];
    bv[0] = b0.x; bv[1] = b0.y; bv[2] = b0.z; bv[3] = b0.w;
    bv[4] = b1.x; bv[5] = b1.y; bv[6] = b1.z; bv[7] = b1.w;
  }
#pragma unroll
  for (int i = 0; i < 4; ++i) {
    int grow = row0 + tm * 4 + i;
    if (grow < M) {
      float o[8];
#pragma unroll
      for (int j = 0; j < 8; ++j) {
        float v = acc[i][j];
        if constexpr (BIAS) v += bv[j];
        o[j] = RELU ? fmaxf(v, 0.f) : v;
      }
      if constexpr (INIT) {
        if constexpr (sizeof(TC) == 2) {
          uint4 pk;
          pk.x = pack2(o[0], o[1]); pk.y = pack2(o[2], o[3]);
          pk.z = pack2(o[4], o[5]); pk.w = pack2(o[6], o[7]);
          *(uint4*)((ushort16*)C + (size_t)grow * CD + tn * 8) = pk;
        } else {
          *(float4*)((float*)C + (size_t)grow * CD + tn * 8) = make_float4(o[0], o[1], o[2], o[3]);
          *(float4*)((float*)C + (size_t)grow * CD + tn * 8 + 4) = make_float4(o[4], o[5], o[6], o[7]);
        }
      } else {
        float* cp = (float*)C + (size_t)grow * CD + tn * 8;
        float4 c0 = *(float4*)cp;
        float4 c1 = *(float4*)(cp + 4);
        *(float4*)cp = make_float4(o[0] + c0.x, o[1] + c0.y, o[2] + c0.z, o[3] + c0.w);
        *(float4*)(cp + 4) = make_float4(o[4] + c1.x, o[5] + c1.y, o[6] + c1.z, o[7] + c1.w);
      }
    }
  }
}

// ---------------- per-row dots with a1_w / a2_w (one wave per row) ----------------
template <typename TH>
__global__ void adot_kernel(const TH* __restrict__ H, int M,
                            const float* __restrict__ a1w, const float* __restrict__ a1b,
                            float* __restrict__ a1out,
                            const float* __restrict__ a2w, const float* __restrict__ a2b,
                            float* __restrict__ a2out) {
  int w = (blockIdx.x * blockDim.x + threadIdx.x) >> 6;
  int lane = threadIdx.x & 63;
  if (w >= M) return;
  float2 h = load2(H, (size_t)w * CD + lane * 2);
  float2 w2 = *(const float2*)(a2w + lane * 2);
  float s2 = h.x * w2.x + h.y * w2.y;
  float s1 = 0.f;
  if (a1out) {
    float2 w1 = *(const float2*)(a1w + lane * 2);
    s1 = h.x * w1.x + h.y * w1.y;
  }
#pragma unroll
  for (int off = 32; off > 0; off >>= 1) {
    s2 += __shfl_down(s2, off, 64);
    s1 += __shfl_down(s1, off, 64);
  }
  if (lane == 0) {
    a2out[w] = s2 + a2b[0];
    if (a1out) a1out[w] = s1 + a1b[0];
  }
}

// ---------------- two-level counting sort of edges by destination bin ----------------
__device__ inline int edge_bin(int e, const int* r0, const int* r1, const int* r2) {
  if (e < CNE) return r0[e];
  if (e < 2 * CNE) return CN0 + r1[e - CNE];
  return 2 * CN0 + r2[e - 2 * CNE];
}
__device__ inline void edge_get(int e, const int* r0, const int* c0, const int* r1,
                                const int* c1, const int* r2, const int* c2,
                                int& bin, int& col) {
  if (e < CNE) { bin = r0[e]; col = c0[e]; }
  else if (e < 2 * CNE) { bin = CN0 + r1[e - CNE]; col = c1[e - CNE]; }
  else { bin = 2 * CN0 + r2[e - 2 * CNE]; col = c2[e - 2 * CNE]; }
}

// P1: per-block coarse histogram -> blockhist[bucket * G + block]
__global__ __launch_bounds__(256) void coarse_hist_kernel(
    const int* __restrict__ r0, const int* __restrict__ r1, const int* __restrict__ r2,
    int* __restrict__ blockhist) {
  __shared__ int lh[NB];
  const int t = threadIdx.x;
  for (int i = t; i < NB; i += 256) lh[i] = 0;
  __syncthreads();
  const int e0 = blockIdx.x * CHUNK;
  for (int i = t; i < CHUNK; i += 256) {
    int e = e0 + i;
    if (e < TOT_E) atomicAdd(&lh[edge_bin(e, r0, r1, r2) >> 9], 1);
  }
  __syncthreads();
  for (int i = t; i < NB; i += 256) blockhist[(size_t)i * G + blockIdx.x] = lh[i];
}

// generic 2-level exclusive scan (in-place), n <= 1024*512
__global__ void scan1g_kernel(int* __restrict__ data, int* __restrict__ bsums, int n) {
  __shared__ int lds[256];
  int t = threadIdx.x;
  int idx0 = blockIdx.x * 1024 + t * 4;
  int v[4];
#pragma unroll
  for (int j = 0; j < 4; ++j) v[j] = (idx0 + j < n) ? data[idx0 + j] : 0;
  int tsum = v[0] + v[1] + v[2] + v[3];
  lds[t] = tsum;
  __syncthreads();
  for (int off = 1; off < 256; off <<= 1) {
    int x = (t >= off) ? lds[t - off] : 0;
    __syncthreads();
    lds[t] += x;
    __syncthreads();
  }
  int run = lds[t] - tsum;
  if (t == 255) bsums[blockIdx.x] = lds[255];
#pragma unroll
  for (int j = 0; j < 4; ++j) {
    if (idx0 + j < n) data[idx0 + j] = run;
    run += v[j];
  }
}

__global__ void scan2g_kernel(int* __restrict__ bsums, int nb) {
  __shared__ int lds[512];
  int t = threadIdx.x;
  int v = (t < nb) ? bsums[t] : 0;
  lds[t] = v;
  __syncthreads();
  for (int off = 1; off < 512; off <<= 1) {
    int x = (t >= off) ? lds[t - off] : 0;
    __syncthreads();
    lds[t] += x;
    __syncthreads();
  }
  if (t < nb) bsums[t] = lds[t] - v;
}

__global__ void scan3g_kernel(int* __restrict__ data, const int* __restrict__ bsums, int n) {
  int t = threadIdx.x;
  int idx0 = blockIdx.x * 1024 + t * 4;
  int off = bsums[blockIdx.x];
#pragma unroll
  for (int j = 0; j < 4; ++j)
    if (idx0 + j < n) data[idx0 + j] += off;
}

// P3: block-coalesced reorder into bucket-grouped packed records (bin_local<<18 | col)
__global__ __launch_bounds__(256) void reorder_kernel(
    const int* __restrict__ r0, const int* __restrict__ c0,
    const int* __restrict__ r1, const int* __restrict__ c1,
    const int* __restrict__ r2, const int* __restrict__ c2,
    const int* __restrict__ blockscan, uint32* __restrict__ bbuf) {
  __shared__ int lbase[NB];
  const int t = threadIdx.x;
  for (int i = t; i < NB; i += 256) lbase[i] = blockscan[(size_t)i * G + blockIdx.x];
  __syncthreads();
  const int e0 = blockIdx.x * CHUNK;
  for (int i = t; i < CHUNK; i += 256) {
    int e = e0 + i;
    if (e >= TOT_E) break;
    int bin, col;
    edge_get(e, r0, c0, r1, c1, r2, c2, bin, col);
    int pos = atomicAdd(&lbase[bin >> 9], 1);
    bbuf[pos] = ((uint32)(bin & 511) << 18) | (uint32)col;
  }
}

// P4: per-bucket LDS counting sort -> final scols + rs (per-bin offsets)
__global__ __launch_bounds__(256) void finalize_kernel(
    const int* __restrict__ blockscan, const uint32* __restrict__ bbuf,
    int* __restrict__ scols, int* __restrict__ rs) {
  __shared__ int lh[512];
  __shared__ int sc[256];
  const int t = threadIdx.x;
  const int b = blockIdx.x;
  const int binbase = b << 9;
  const int gs = blockscan[(size_t)b * G];
  const int ge = (b == NB - 1) ? TOT_E : blockscan[(size_t)(b + 1) * G];
  const int cnt = ge - gs;

  lh[2 * t] = 0;
  lh[2 * t + 1] = 0;
  __syncthreads();
  for (int i = t; i < cnt; i += 256) atomicAdd(&lh[bbuf[gs + i] >> 18], 1);
  __syncthreads();
  // exclusive scan of lh[0..511]
  int v0 = lh[2 * t], v1 = lh[2 * t + 1];
  int tsum = v0 + v1;
  sc[t] = tsum;
  __syncthreads();
  for (int off = 1; off < 256; off <<= 1) {
    int x = (t >= off) ? sc[t - off] : 0;
    __syncthreads();
    sc[t] += x;
    __syncthreads();
  }
  int ex = sc[t] - tsum;
  lh[2 * t] = ex;
  lh[2 * t + 1] = ex + v0;
  // emit global per-bin offsets
  int nb_here = NBINS - binbase;  // bins in this bucket (<=512)
  if (2 * t < nb_here && 2 * t < 512) rs[binbase + 2 * t] = gs + ex;
  if (2 * t + 1 < nb_here && 2 * t + 1 < 512) rs[binbase + 2 * t + 1] = gs + ex + v0;
  if (b == NB - 1 && t == 255) rs[NBINS] = TOT_E;
  __syncthreads();
  // scatter (write window = this bucket's ~20KB region -> L2-resident)
  for (int i = t; i < cnt; i += 256) {
    uint32 p = bbuf[gs + i];
    int pos = atomicAdd(&lh[p >> 18], 1);
    scols[gs + pos] = (int)(p & 0x3FFFFu);
  }
}

// ---------------- attention aggregation: one wave per row of one adjacency ----------
template <typename TX>
__global__ void agg_kernel(const int* __restrict__ rs_base, const int* __restrict__ scols,
                           const TX* __restrict__ xj, const float* __restrict__ a1_0,
                           const float* __restrict__ a2, ushort16* __restrict__ aggout) {
  int w = (blockIdx.x * blockDim.x + threadIdx.x) >> 6;
  if (w >= CN0) return;
  int lane = threadIdx.x & 63;
  int s = rs_base[w], e = rs_base[w + 1];
  float a1v = a1_0[w];
  float accx = 0.f, accy = 0.f;
  for (int p = s; p < e; ++p) {
    int col = scols[p];
    float z = a1v + a2[col];
    float att = 1.0f / (1.0f + __expf(-z));
    float2 xv = load2(xj, (size_t)col * CD + lane * 2);
    accx = fmaf(att, xv.x, accx);
    accy = fmaf(att, xv.y, accy);
  }
  *(uint32*)(aggout + (size_t)w * CD + lane * 2) = pack2(accx, accy);
}

// ---------------- launch ----------------
extern "C" void kernel_launch(void* const* d_in, const int* in_sizes, int n_in,
                              void* d_out, int out_size, void* d_ws, size_t ws_size,
                              hipStream_t stream) {
  const float* x0 = (const float*)d_in[0];
  const float* x1 = (const float*)d_in[1];
  const float* x2 = (const float*)d_in[2];
  const float* W1 = (const float*)d_in[3];
  const float* b1 = (const float*)d_in[4];
  const float* a1_w = (const float*)d_in[5];
  const float* a1_b = (const float*)d_in[6];
  const float* a2_w = (const float*)d_in[7];
  const float* a2_b = (const float*)d_in[8];
  const float* Wagg = (const float*)d_in[9];
  const float* bagg = (const float*)d_in[10];
  const int* adj0_r = (const int*)d_in[11];
  const int* adj0_c = (const int*)d_in[12];
  const int* adj1_r = (const int*)d_in[13];
  const int* adj1_c = (const int*)d_in[14];
  const int* adj2_r = (const int*)d_in[15];
  const int* adj2_c = (const int*)d_in[16];
  float* out = (float*)d_out;

  if (ws_size < OFF_END) return;  // tripwire

  char* ws = (char*)d_ws;
  ushort16* h0b    = (ushort16*)(ws + OFF_H0B);
  ushort16* h1b    = (ushort16*)(ws + OFF_H1B);
  ushort16* h2b    = (ushort16*)(ws + OFF_H2B);
  ushort16* aggbuf = (ushort16*)(ws + OFF_AGG);
  float*    a1_0   = (float*)(ws + OFF_A1);
  float*    a2all  = (float*)(ws + OFF_A2);
  int*      rs     = (int*)(ws + OFF_RS);
  int*      bh     = (int*)(ws + OFF_BH);
  uint32*   bbuf   = (uint32*)(ws + OFF_BB);
  int*      scols  = (int*)(ws + OFF_SCL);
  int*      bsums  = (int*)(ws + OFF_BS);

  // 1) lin1: h = relu(x @ W1 + b1), bf16 outputs
  gemm_kernel<true, true, true, float, ushort16>
      <<<(CN0 + 63) / 64, 256, 0, stream>>>(x0, W1, b1, h0b, CN0);
  gemm_kernel<true, true, true, float, ushort16>
      <<<(CN1 + 63) / 64, 256, 0, stream>>>(x1, W1, b1, h1b, CN1);
  gemm_kernel<true, true, true, float, ushort16>
      <<<(CN2 + 63) / 64, 256, 0, stream>>>(x2, W1, b1, h2b, CN2);

  // 2) attention scalars
  adot_kernel<ushort16><<<(CN0 * 64 + 255) / 256, 256, 0, stream>>>(
      h0b, CN0, a1_w, a1_b, a1_0, a2_w, a2_b, a2all);
  adot_kernel<ushort16><<<(CN1 * 64 + 255) / 256, 256, 0, stream>>>(
      h1b, CN1, nullptr, nullptr, nullptr, a2_w, a2_b, a2all + CN0);
  adot_kernel<ushort16><<<(CN2 * 64 + 255) / 256, 256, 0, stream>>>(
      h2b, CN2, nullptr, nullptr, nullptr, a2_w, a2_b, a2all + CN0 + CN1);

  // 3) two-level counting sort of all 3 edge lists by destination bin
  coarse_hist_kernel<<<G, 256, 0, stream>>>(adj0_r, adj1_r, adj2_r, bh);
  scan1g_kernel<<<CSCAN_BLOCKS, 256, 0, stream>>>(bh, bsums, NBG);
  scan2g_kernel<<<1, 512, 0, stream>>>(bsums, CSCAN_BLOCKS);
  scan3g_kernel<<<CSCAN_BLOCKS, 256, 0, stream>>>(bh, bsums, NBG);
  reorder_kernel<<<G, 256, 0, stream>>>(adj0_r, adj0_c, adj1_r, adj1_c,
                                        adj2_r, adj2_c, bh, bbuf);
  finalize_kernel<<<NB, 256, 0, stream>>>(bh, bbuf, scols, rs);

  // 4) out = h0 @ Wagg[0:128] + bagg
  gemm_kernel<false, true, true, ushort16, float>
      <<<(CN0 + 63) / 64, 256, 0, stream>>>(h0b, Wagg, bagg, out, CN0);

  // 5) per adjacency: agg into aggbuf (bf16), then out += aggbuf @ Wagg panel
  agg_kernel<ushort16><<<(CN0 * 64 + 255) / 256, 256, 0, stream>>>(
      rs, scols, h0b, a1_0, a2all, aggbuf);
  gemm_kernel<false, false, false, ushort16, float>
      <<<(CN0 + 63) / 64, 256, 0, stream>>>(aggbuf, Wagg + 1 * CD * CD, nullptr, out, CN0);

  agg_kernel<ushort16><<<(CN0 * 64 + 255) / 256, 256, 0, stream>>>(
      rs + CN0, scols, h1b, a1_0, a2all + CN0, aggbuf);
  gemm_kernel<false, false, false, ushort16, float>
      <<<(CN0 + 63) / 64, 256, 0, stream>>>(aggbuf, Wagg + 2 * CD * CD, nullptr, out, CN0);

  agg_kernel<ushort16><<<(CN0 * 64 + 255) / 256, 256, 0, stream>>>(
      rs + 2 * CN0, scols, h2b, a1_0, a2all + CN0 + CN1, aggbuf);
  gemm_kernel<false, false, false, ushort16, float>
      <<<(CN0 + 63) / 64, 256, 0, stream>>>(aggbuf, Wagg + 3 * CD * CD, nullptr, out, CN0);
}

// Round 4
// 754.122 us; speedup vs baseline: 1.9114x; 1.4958x over previous
//
#include <hip/hip_runtime.h>

typedef unsigned int uint32;
typedef unsigned short ushort16;

// Problem constants
constexpr int CN0 = 100000;
constexpr int CN1 = 150000;
constexpr int CN2 = 80000;
constexpr int CNE = 1000000;
constexpr int CD  = 128;
constexpr int NBINS = 3 * CN0;                  // 300000 rows across 3 adjacencies
constexpr int TOT_E = 3 * CNE;

// two-level sort params
constexpr int NB    = (NBINS + 511) / 512;      // 586 coarse buckets (bin>>9)
constexpr int CHUNK = 8192;                     // edges per block in hist/reorder
constexpr int G     = (TOT_E + CHUNK - 1) / CHUNK;  // 367 blocks
constexpr int NBG   = NB * G;                   // bucket-major block hist
constexpr int CSCAN_BLOCKS = (NBG + 1023) / 1024;

constexpr size_t align256(size_t x) { return (x + 255) & ~(size_t)255; }

// ---------------- workspace layout (bytes) — peak ~177 MB ----------------
constexpr size_t OFF_H0B = 0;                                          // CN0*CD bf16
constexpr size_t OFF_H1B = align256(OFF_H0B + (size_t)CN0 * CD * 2);   // CN1*CD bf16
constexpr size_t OFF_H2B = align256(OFF_H1B + (size_t)CN1 * CD * 2);   // CN2*CD bf16
constexpr size_t OFF_AG1 = align256(OFF_H2B + (size_t)CN2 * CD * 2);   // CN0*CD bf16
constexpr size_t OFF_AG2 = align256(OFF_AG1 + (size_t)CN0 * CD * 2);   // CN0*CD bf16
constexpr size_t OFF_A1  = align256(OFF_AG2 + (size_t)CN0 * CD * 2);
constexpr size_t OFF_A2  = align256(OFF_A1 + (size_t)CN0 * 4);
constexpr size_t OFF_RS  = align256(OFF_A2 + (size_t)(CN0 + CN1 + CN2) * 4); // NBINS+1
constexpr size_t OFF_BH  = align256(OFF_RS + (size_t)(NBINS + 1) * 4);       // NBG ints
constexpr size_t OFF_SCL = align256(OFF_BH + (size_t)NBG * 4);               // TOT_E int
constexpr size_t OFF_BS  = align256(OFF_SCL + (size_t)TOT_E * 4);
// overlay region: bbuf (TOT_E u32, live only during sort) then agg0 panel (CN0*CD bf16)
constexpr size_t OFF_BB  = align256(OFF_BS + (size_t)CSCAN_BLOCKS * 4);
constexpr size_t OFF_END = OFF_BB + (size_t)CN0 * CD * 2;  // agg0 panel > bbuf size? no:
// bbuf needs TOT_E*4 = 12 MB; agg0 needs 25.6 MB -> region = max = 25.6 MB. (CN0*CD*2 > TOT_E*4)

// ---------------- bf16 helpers ----------------
__device__ inline float b2f(ushort16 u) {
  union { uint32 i; float f; } v; v.i = ((uint32)u) << 16; return v.f;
}
__device__ inline ushort16 f2b(float f) {
  union { float f; uint32 i; } v; v.f = f;
  uint32 r = (v.i + 0x7FFFu + ((v.i >> 16) & 1u)) >> 16;
  return (ushort16)r;
}
__device__ inline uint32 pack2(float a, float b) {
  return (uint32)f2b(a) | ((uint32)f2b(b) << 16);
}
__device__ inline float2 load2(const ushort16* p, size_t i) {
  uint32 u = *(const uint32*)(p + i);
  union { uint32 i; float f; } lo, hi;
  lo.i = u << 16; hi.i = u & 0xFFFF0000u;
  return make_float2(lo.f, hi.f);
}

// ---------------- MFMA types ----------------
typedef __bf16 bf16x8 __attribute__((ext_vector_type(8)));
typedef float f32x4 __attribute__((ext_vector_type(4)));
union FragU { uint4 q; bf16x8 v; ushort16 u[8]; };

// ---------------- MFMA GEMM: C[M x 128] = concat_K(A panels) @ W (+bias) ------------
// NP K-panels of 128 each; A panels row-major [M x 128]; W row-major [NP*128 x 128] fp32.
// Per block: 64 rows (4 waves x 16). B staged in LDS transposed bf16. A direct from global.
// Optional fused row-dots with a1w/a2w (on post-activation output) -> dot1out/dot2out.
template <int NP, bool RELU, bool DOT1, bool DOT2, typename TA, typename TC>
__global__ __launch_bounds__(256) void gemm_mfma(
    const TA* __restrict__ A0, const TA* __restrict__ A1,
    const TA* __restrict__ A2, const TA* __restrict__ A3,
    const float* __restrict__ W, const float* __restrict__ bias,
    TC* __restrict__ C, int M,
    const float* __restrict__ a1w, const float* __restrict__ a2w,
    const float* __restrict__ a1b, const float* __restrict__ a2b,
    float* __restrict__ dot1out, float* __restrict__ dot2out) {
  constexpr int WS = 136;  // Wt row stride (bf16 elems), 16B-aligned, +8 pad
  __shared__ ushort16 Wt[128 * WS];

  const int t = threadIdx.x;
  const int wave = t >> 6;
  const int lane = t & 63;
  const int ln = lane & 15;
  const int quad = lane >> 4;
  const int row0 = blockIdx.x * 64;
  const int rowA = row0 + wave * 16 + ln;          // A-fragment row
  const int rA = (rowA < M) ? rowA : (M - 1);      // clamp (garbage rows never stored)
  const int rowC = row0 + wave * 16 + quad * 4;    // C rows rowC..rowC+3

  f32x4 acc[8];
#pragma unroll
  for (int j = 0; j < 8; ++j) acc[j] = (f32x4)(0.f);

#pragma unroll
  for (int p = 0; p < NP; ++p) {
    const TA* __restrict__ Ap = (p == 0) ? A0 : ((p == 1) ? A1 : ((p == 2) ? A2 : A3));
    const float* __restrict__ Wp = W + (size_t)p * CD * CD;
    if (p > 0) __syncthreads();
    // stage W panel -> LDS transposed bf16: Wt[n][k]
    for (int i = t; i < CD * CD; i += 256) {
      int k = i >> 7, n = i & 127;
      Wt[n * WS + k] = f2b(Wp[i]);
    }
    __syncthreads();
#pragma unroll
    for (int ks = 0; ks < 4; ++ks) {
      const int k0 = ks * 32;
      FragU af;
      if constexpr (sizeof(TA) == 2) {
        af.q = *(const uint4*)((const ushort16*)Ap + (size_t)rA * CD + k0 + quad * 8);
      } else {
        const float* ap = (const float*)Ap + (size_t)rA * CD + k0 + quad * 8;
        float4 f0 = *(const float4*)ap;
        float4 f1 = *(const float4*)(ap + 4);
        af.u[0] = f2b(f0.x); af.u[1] = f2b(f0.y); af.u[2] = f2b(f0.z); af.u[3] = f2b(f0.w);
        af.u[4] = f2b(f1.x); af.u[5] = f2b(f1.y); af.u[6] = f2b(f1.z); af.u[7] = f2b(f1.w);
      }
#pragma unroll
      for (int j = 0; j < 8; ++j) {
        FragU bf;
        bf.q = *(const uint4*)&Wt[(j * 16 + ln) * WS + k0 + quad * 8];
        acc[j] = __builtin_amdgcn_mfma_f32_16x16x32_bf16(af.v, bf.v, acc[j], 0, 0, 0);
      }
    }
  }

  // epilogue: bias, activation, store, fused dots
  float s1[4] = {0.f, 0.f, 0.f, 0.f};
  float s2[4] = {0.f, 0.f, 0.f, 0.f};
#pragma unroll
  for (int j = 0; j < 8; ++j) {
    const int n = j * 16 + ln;
    const float bj = bias[n];
    const float a1wj = DOT1 ? a1w[n] : 0.f;
    const float a2wj = DOT2 ? a2w[n] : 0.f;
#pragma unroll
    for (int r = 0; r < 4; ++r) {
      float v = acc[j][r] + bj;
      if constexpr (RELU) v = fmaxf(v, 0.f);
      const int row = rowC + r;
      if (row < M) {
        if constexpr (sizeof(TC) == 2)
          ((ushort16*)C)[(size_t)row * CD + n] = f2b(v);
        else
          ((float*)C)[(size_t)row * CD + n] = v;
      }
      if constexpr (DOT1) s1[r] = fmaf(v, a1wj, s1[r]);
      if constexpr (DOT2) s2[r] = fmaf(v, a2wj, s2[r]);
    }
  }
  if constexpr (DOT1 || DOT2) {
#pragma unroll
    for (int mask = 1; mask < 16; mask <<= 1) {
#pragma unroll
      for (int r = 0; r < 4; ++r) {
        if constexpr (DOT1) s1[r] += __shfl_xor(s1[r], mask);
        if constexpr (DOT2) s2[r] += __shfl_xor(s2[r], mask);
      }
    }
    if (ln == 0) {
#pragma unroll
      for (int r = 0; r < 4; ++r) {
        const int row = rowC + r;
        if (row < M) {
          if constexpr (DOT2) dot2out[row] = s2[r] + a2b[0];
          if constexpr (DOT1) dot1out[row] = s1[r] + a1b[0];
        }
      }
    }
  }
}

// ---------------- two-level counting sort of edges by destination bin ----------------
__device__ inline int edge_bin(int e, const int* r0, const int* r1, const int* r2) {
  if (e < CNE) return r0[e];
  if (e < 2 * CNE) return CN0 + r1[e - CNE];
  return 2 * CN0 + r2[e - 2 * CNE];
}
__device__ inline void edge_get(int e, const int* r0, const int* c0, const int* r1,
                                const int* c1, const int* r2, const int* c2,
                                int& bin, int& col) {
  if (e < CNE) { bin = r0[e]; col = c0[e]; }
  else if (e < 2 * CNE) { bin = CN0 + r1[e - CNE]; col = c1[e - CNE]; }
  else { bin = 2 * CN0 + r2[e - 2 * CNE]; col = c2[e - 2 * CNE]; }
}

__global__ __launch_bounds__(256) void coarse_hist_kernel(
    const int* __restrict__ r0, const int* __restrict__ r1, const int* __restrict__ r2,
    int* __restrict__ blockhist) {
  __shared__ int lh[NB];
  const int t = threadIdx.x;
  for (int i = t; i < NB; i += 256) lh[i] = 0;
  __syncthreads();
  const int e0 = blockIdx.x * CHUNK;
  for (int i = t; i < CHUNK; i += 256) {
    int e = e0 + i;
    if (e < TOT_E) atomicAdd(&lh[edge_bin(e, r0, r1, r2) >> 9], 1);
  }
  __syncthreads();
  for (int i = t; i < NB; i += 256) blockhist[(size_t)i * G + blockIdx.x] = lh[i];
}

__global__ void scan1g_kernel(int* __restrict__ data, int* __restrict__ bsums, int n) {
  __shared__ int lds[256];
  int t = threadIdx.x;
  int idx0 = blockIdx.x * 1024 + t * 4;
  int v[4];
#pragma unroll
  for (int j = 0; j < 4; ++j) v[j] = (idx0 + j < n) ? data[idx0 + j] : 0;
  int tsum = v[0] + v[1] + v[2] + v[3];
  lds[t] = tsum;
  __syncthreads();
  for (int off = 1; off < 256; off <<= 1) {
    int x = (t >= off) ? lds[t - off] : 0;
    __syncthreads();
    lds[t] += x;
    __syncthreads();
  }
  int run = lds[t] - tsum;
  if (t == 255) bsums[blockIdx.x] = lds[255];
#pragma unroll
  for (int j = 0; j < 4; ++j) {
    if (idx0 + j < n) data[idx0 + j] = run;
    run += v[j];
  }
}

__global__ void scan2g_kernel(int* __restrict__ bsums, int nb) {
  __shared__ int lds[512];
  int t = threadIdx.x;
  int v = (t < nb) ? bsums[t] : 0;
  lds[t] = v;
  __syncthreads();
  for (int off = 1; off < 512; off <<= 1) {
    int x = (t >= off) ? lds[t - off] : 0;
    __syncthreads();
    lds[t] += x;
    __syncthreads();
  }
  if (t < nb) bsums[t] = lds[t] - v;
}

__global__ void scan3g_kernel(int* __restrict__ data, const int* __restrict__ bsums, int n) {
  int t = threadIdx.x;
  int idx0 = blockIdx.x * 1024 + t * 4;
  int off = bsums[blockIdx.x];
#pragma unroll
  for (int j = 0; j < 4; ++j)
    if (idx0 + j < n) data[idx0 + j] += off;
}

__global__ __launch_bounds__(256) void reorder_kernel(
    const int* __restrict__ r0, const int* __restrict__ c0,
    const int* __restrict__ r1, const int* __restrict__ c1,
    const int* __restrict__ r2, const int* __restrict__ c2,
    const int* __restrict__ blockscan, uint32* __restrict__ bbuf) {
  __shared__ int lbase[NB];
  const int t = threadIdx.x;
  for (int i = t; i < NB; i += 256) lbase[i] = blockscan[(size_t)i * G + blockIdx.x];
  __syncthreads();
  const int e0 = blockIdx.x * CHUNK;
  for (int i = t; i < CHUNK; i += 256) {
    int e = e0 + i;
    if (e >= TOT_E) break;
    int bin, col;
    edge_get(e, r0, c0, r1, c1, r2, c2, bin, col);
    int pos = atomicAdd(&lbase[bin >> 9], 1);
    bbuf[pos] = ((uint32)(bin & 511) << 18) | (uint32)col;
  }
}

__global__ __launch_bounds__(256) void finalize_kernel(
    const int* __restrict__ blockscan, const uint32* __restrict__ bbuf,
    int* __restrict__ scols, int* __restrict__ rs) {
  __shared__ int lh[512];
  __shared__ int sc[256];
  const int t = threadIdx.x;
  const int b = blockIdx.x;
  const int binbase = b << 9;
  const int gs = blockscan[(size_t)b * G];
  const int ge = (b == NB - 1) ? TOT_E : blockscan[(size_t)(b + 1) * G];
  const int cnt = ge - gs;

  lh[2 * t] = 0;
  lh[2 * t + 1] = 0;
  __syncthreads();
  for (int i = t; i < cnt; i += 256) atomicAdd(&lh[bbuf[gs + i] >> 18], 1);
  __syncthreads();
  int v0 = lh[2 * t], v1 = lh[2 * t + 1];
  int tsum = v0 + v1;
  sc[t] = tsum;
  __syncthreads();
  for (int off = 1; off < 256; off <<= 1) {
    int x = (t >= off) ? sc[t - off] : 0;
    __syncthreads();
    sc[t] += x;
    __syncthreads();
  }
  int ex = sc[t] - tsum;
  lh[2 * t] = ex;
  lh[2 * t + 1] = ex + v0;
  int nb_here = NBINS - binbase;
  if (2 * t < nb_here) rs[binbase + 2 * t] = gs + ex;
  if (2 * t + 1 < nb_here) rs[binbase + 2 * t + 1] = gs + ex + v0;
  if (b == NB - 1 && t == 255) rs[NBINS] = TOT_E;
  __syncthreads();
  for (int i = t; i < cnt; i += 256) {
    uint32 p = bbuf[gs + i];
    int pos = atomicAdd(&lh[p >> 18], 1);
    scols[gs + pos] = (int)(p & 0x3FFFFu);
  }
}

// ---------------- attention aggregation: one wave per row of one adjacency ----------
__global__ void agg_kernel(const int* __restrict__ rs_base, const int* __restrict__ scols,
                           const ushort16* __restrict__ xj, const float* __restrict__ a1_0,
                           const float* __restrict__ a2, ushort16* __restrict__ aggout) {
  int w = (blockIdx.x * blockDim.x + threadIdx.x) >> 6;
  if (w >= CN0) return;
  int lane = threadIdx.x & 63;
  int s = rs_base[w], e = rs_base[w + 1];
  float a1v = a1_0[w];
  float accx = 0.f, accy = 0.f;
  for (int p = s; p < e; ++p) {
    int col = scols[p];
    float z = a1v + a2[col];
    float att = 1.0f / (1.0f + __expf(-z));
    float2 xv = load2(xj, (size_t)col * CD + lane * 2);
    accx = fmaf(att, xv.x, accx);
    accy = fmaf(att, xv.y, accy);
  }
  *(uint32*)(aggout + (size_t)w * CD + lane * 2) = pack2(accx, accy);
}

// ---------------- launch ----------------
extern "C" void kernel_launch(void* const* d_in, const int* in_sizes, int n_in,
                              void* d_out, int out_size, void* d_ws, size_t ws_size,
                              hipStream_t stream) {
  const float* x0 = (const float*)d_in[0];
  const float* x1 = (const float*)d_in[1];
  const float* x2 = (const float*)d_in[2];
  const float* W1 = (const float*)d_in[3];
  const float* b1 = (const float*)d_in[4];
  const float* a1_w = (const float*)d_in[5];
  const float* a1_b = (const float*)d_in[6];
  const float* a2_w = (const float*)d_in[7];
  const float* a2_b = (const float*)d_in[8];
  const float* Wagg = (const float*)d_in[9];
  const float* bagg = (const float*)d_in[10];
  const int* adj0_r = (const int*)d_in[11];
  const int* adj0_c = (const int*)d_in[12];
  const int* adj1_r = (const int*)d_in[13];
  const int* adj1_c = (const int*)d_in[14];
  const int* adj2_r = (const int*)d_in[15];
  const int* adj2_c = (const int*)d_in[16];
  float* out = (float*)d_out;

  if (ws_size < OFF_END) return;  // tripwire

  char* ws = (char*)d_ws;
  ushort16* h0b    = (ushort16*)(ws + OFF_H0B);
  ushort16* h1b    = (ushort16*)(ws + OFF_H1B);
  ushort16* h2b    = (ushort16*)(ws + OFF_H2B);
  ushort16* agg1b  = (ushort16*)(ws + OFF_AG1);
  ushort16* agg2b  = (ushort16*)(ws + OFF_AG2);
  float*    a1_0   = (float*)(ws + OFF_A1);
  float*    a2all  = (float*)(ws + OFF_A2);
  int*      rs     = (int*)(ws + OFF_RS);
  int*      bh     = (int*)(ws + OFF_BH);
  int*      scols  = (int*)(ws + OFF_SCL);
  int*      bsums  = (int*)(ws + OFF_BS);
  uint32*   bbuf   = (uint32*)(ws + OFF_BB);     // live only during sort
  ushort16* agg0b  = (ushort16*)(ws + OFF_BB);   // overlays bbuf after finalize

  // 1) lin1: h = relu(x @ W1 + b1) -> bf16, with fused a1/a2 row-dots
  gemm_mfma<1, true, true, true, float, ushort16><<<(CN0 + 63) / 64, 256, 0, stream>>>(
      x0, x0, x0, x0, W1, b1, h0b, CN0, a1_w, a2_w, a1_b, a2_b, a1_0, a2all);
  gemm_mfma<1, true, false, true, float, ushort16><<<(CN1 + 63) / 64, 256, 0, stream>>>(
      x1, x1, x1, x1, W1, b1, h1b, CN1, a1_w, a2_w, a1_b, a2_b, a1_0, a2all + CN0);
  gemm_mfma<1, true, false, true, float, ushort16><<<(CN2 + 63) / 64, 256, 0, stream>>>(
      x2, x2, x2, x2, W1, b1, h2b, CN2, a1_w, a2_w, a1_b, a2_b, a1_0, a2all + CN0 + CN1);

  // 2) two-level counting sort of all 3 edge lists by destination bin
  coarse_hist_kernel<<<G, 256, 0, stream>>>(adj0_r, adj1_r, adj2_r, bh);
  scan1g_kernel<<<CSCAN_BLOCKS, 256, 0, stream>>>(bh, bsums, NBG);
  scan2g_kernel<<<1, 512, 0, stream>>>(bsums, CSCAN_BLOCKS);
  scan3g_kernel<<<CSCAN_BLOCKS, 256, 0, stream>>>(bh, bsums, NBG);
  reorder_kernel<<<G, 256, 0, stream>>>(adj0_r, adj0_c, adj1_r, adj1_c,
                                        adj2_r, adj2_c, bh, bbuf);
  finalize_kernel<<<NB, 256, 0, stream>>>(bh, bbuf, scols, rs);

  // 3) aggregation panels (agg0b overlays bbuf — safe after finalize)
  agg_kernel<<<(CN0 * 64 + 255) / 256, 256, 0, stream>>>(
      rs, scols, h0b, a1_0, a2all, agg0b);
  agg_kernel<<<(CN0 * 64 + 255) / 256, 256, 0, stream>>>(
      rs + CN0, scols, h1b, a1_0, a2all + CN0, agg1b);
  agg_kernel<<<(CN0 * 64 + 255) / 256, 256, 0, stream>>>(
      rs + 2 * CN0, scols, h2b, a1_0, a2all + CN0 + CN1, agg2b);

  // 4) out = [h0 | agg0 | agg1 | agg2] @ Wagg + bagg  (single K=512 MFMA GEMM)
  gemm_mfma<4, false, false, false, ushort16, float><<<(CN0 + 63) / 64, 256, 0, stream>>>(
      h0b, agg0b, agg1b, agg2b, Wagg, bagg, out, CN0,
      a1_w, a2_w, a1_b, a2_b, nullptr, nullptr);
}

// Round 5
// 589.363 us; speedup vs baseline: 2.4457x; 1.2796x over previous
//
#include <hip/hip_runtime.h>

typedef unsigned int uint32;
typedef unsigned short ushort16;

// Problem constants
constexpr int CN0 = 100000;
constexpr int CN1 = 150000;
constexpr int CN2 = 80000;
constexpr int CNE = 1000000;
constexpr int CD  = 128;
constexpr int NBINS = 3 * CN0;                  // 300000 rows across 3 adjacencies
constexpr int TOT_E = 3 * CNE;

// two-level sort params
constexpr int NB    = (NBINS + 511) / 512;      // 586 coarse buckets (bin>>9)
constexpr int CHUNK = 8192;                     // edges per block in hist/reorder
constexpr int G     = (TOT_E + CHUNK - 1) / CHUNK;  // 367 blocks
constexpr int NBG   = NB * G;                   // bucket-major block hist
constexpr int CSCAN_BLOCKS = (NBG + 1023) / 1024;

constexpr size_t align256(size_t x) { return (x + 255) & ~(size_t)255; }

// ---------------- workspace layout (bytes) — peak ~177 MB ----------------
constexpr size_t OFF_H0B = 0;                                          // CN0*CD bf16
constexpr size_t OFF_H1B = align256(OFF_H0B + (size_t)CN0 * CD * 2);   // CN1*CD bf16
constexpr size_t OFF_H2B = align256(OFF_H1B + (size_t)CN1 * CD * 2);   // CN2*CD bf16
constexpr size_t OFF_AG1 = align256(OFF_H2B + (size_t)CN2 * CD * 2);   // CN0*CD bf16
constexpr size_t OFF_AG2 = align256(OFF_AG1 + (size_t)CN0 * CD * 2);   // CN0*CD bf16
constexpr size_t OFF_A1  = align256(OFF_AG2 + (size_t)CN0 * CD * 2);
constexpr size_t OFF_A2  = align256(OFF_A1 + (size_t)CN0 * 4);
constexpr size_t OFF_RS  = align256(OFF_A2 + (size_t)(CN0 + CN1 + CN2) * 4); // NBINS+1
constexpr size_t OFF_BH  = align256(OFF_RS + (size_t)(NBINS + 1) * 4);       // NBG ints
constexpr size_t OFF_SCL = align256(OFF_BH + (size_t)NBG * 4);               // TOT_E u32
constexpr size_t OFF_BS  = align256(OFF_SCL + (size_t)TOT_E * 4);
// overlay region: bbuf (TOT_E u32, live only during sort) then agg0 panel (CN0*CD bf16)
constexpr size_t OFF_BB  = align256(OFF_BS + (size_t)CSCAN_BLOCKS * 4);
constexpr size_t OFF_END = OFF_BB + (size_t)CN0 * CD * 2;  // 25.6 MB > bbuf's 12 MB

// ---------------- bf16 helpers ----------------
__device__ inline float b2f(ushort16 u) {
  union { uint32 i; float f; } v; v.i = ((uint32)u) << 16; return v.f;
}
__device__ inline ushort16 f2b(float f) {
  union { float f; uint32 i; } v; v.f = f;
  uint32 r = (v.i + 0x7FFFu + ((v.i >> 16) & 1u)) >> 16;
  return (ushort16)r;
}
__device__ inline uint32 pack2(float a, float b) {
  return (uint32)f2b(a) | ((uint32)f2b(b) << 16);
}
__device__ inline float2 load2(const ushort16* p, size_t i) {
  uint32 u = *(const uint32*)(p + i);
  union { uint32 i; float f; } lo, hi;
  lo.i = u << 16; hi.i = u & 0xFFFF0000u;
  return make_float2(lo.f, hi.f);
}

// ---------------- MFMA types ----------------
typedef __bf16 bf16x8 __attribute__((ext_vector_type(8)));
typedef float f32x4 __attribute__((ext_vector_type(4)));
union FragU { uint4 q; bf16x8 v; ushort16 u[8]; };

// ---------------- MFMA GEMM: C[M x 128] = concat_K(A panels) @ W (+bias) ------------
template <int NP, bool RELU, bool DOT1, bool DOT2, typename TA, typename TC>
__global__ __launch_bounds__(256) void gemm_mfma(
    const TA* __restrict__ A0, const TA* __restrict__ A1,
    const TA* __restrict__ A2, const TA* __restrict__ A3,
    const float* __restrict__ W, const float* __restrict__ bias,
    TC* __restrict__ C, int M,
    const float* __restrict__ a1w, const float* __restrict__ a2w,
    const float* __restrict__ a1b, const float* __restrict__ a2b,
    float* __restrict__ dot1out, float* __restrict__ dot2out) {
  constexpr int WS = 136;  // Wt row stride (bf16 elems), 16B-aligned, +8 pad
  __shared__ ushort16 Wt[128 * WS];

  const int t = threadIdx.x;
  const int wave = t >> 6;
  const int lane = t & 63;
  const int ln = lane & 15;
  const int quad = lane >> 4;
  const int row0 = blockIdx.x * 64;
  const int rowA = row0 + wave * 16 + ln;          // A-fragment row
  const int rA = (rowA < M) ? rowA : (M - 1);      // clamp (garbage rows never stored)
  const int rowC = row0 + wave * 16 + quad * 4;    // C rows rowC..rowC+3

  f32x4 acc[8];
#pragma unroll
  for (int j = 0; j < 8; ++j) acc[j] = (f32x4)(0.f);

#pragma unroll
  for (int p = 0; p < NP; ++p) {
    const TA* __restrict__ Ap = (p == 0) ? A0 : ((p == 1) ? A1 : ((p == 2) ? A2 : A3));
    const float* __restrict__ Wp = W + (size_t)p * CD * CD;
    if (p > 0) __syncthreads();
    for (int i = t; i < CD * CD; i += 256) {
      int k = i >> 7, n = i & 127;
      Wt[n * WS + k] = f2b(Wp[i]);
    }
    __syncthreads();
#pragma unroll
    for (int ks = 0; ks < 4; ++ks) {
      const int k0 = ks * 32;
      FragU af;
      if constexpr (sizeof(TA) == 2) {
        af.q = *(const uint4*)((const ushort16*)Ap + (size_t)rA * CD + k0 + quad * 8);
      } else {
        const float* ap = (const float*)Ap + (size_t)rA * CD + k0 + quad * 8;
        float4 f0 = *(const float4*)ap;
        float4 f1 = *(const float4*)(ap + 4);
        af.u[0] = f2b(f0.x); af.u[1] = f2b(f0.y); af.u[2] = f2b(f0.z); af.u[3] = f2b(f0.w);
        af.u[4] = f2b(f1.x); af.u[5] = f2b(f1.y); af.u[6] = f2b(f1.z); af.u[7] = f2b(f1.w);
      }
#pragma unroll
      for (int j = 0; j < 8; ++j) {
        FragU bf;
        bf.q = *(const uint4*)&Wt[(j * 16 + ln) * WS + k0 + quad * 8];
        acc[j] = __builtin_amdgcn_mfma_f32_16x16x32_bf16(af.v, bf.v, acc[j], 0, 0, 0);
      }
    }
  }

  // epilogue: bias, activation, store, fused dots
  float s1[4] = {0.f, 0.f, 0.f, 0.f};
  float s2[4] = {0.f, 0.f, 0.f, 0.f};
#pragma unroll
  for (int j = 0; j < 8; ++j) {
    const int n = j * 16 + ln;
    const float bj = bias[n];
    const float a1wj = DOT1 ? a1w[n] : 0.f;
    const float a2wj = DOT2 ? a2w[n] : 0.f;
#pragma unroll
    for (int r = 0; r < 4; ++r) {
      float v = acc[j][r] + bj;
      if constexpr (RELU) v = fmaxf(v, 0.f);
      const int row = rowC + r;
      if (row < M) {
        if constexpr (sizeof(TC) == 2)
          ((ushort16*)C)[(size_t)row * CD + n] = f2b(v);
        else
          ((float*)C)[(size_t)row * CD + n] = v;
      }
      if constexpr (DOT1) s1[r] = fmaf(v, a1wj, s1[r]);
      if constexpr (DOT2) s2[r] = fmaf(v, a2wj, s2[r]);
    }
  }
  if constexpr (DOT1 || DOT2) {
#pragma unroll
    for (int mask = 1; mask < 16; mask <<= 1) {
#pragma unroll
      for (int r = 0; r < 4; ++r) {
        if constexpr (DOT1) s1[r] += __shfl_xor(s1[r], mask);
        if constexpr (DOT2) s2[r] += __shfl_xor(s2[r], mask);
      }
    }
    if (ln == 0) {
#pragma unroll
      for (int r = 0; r < 4; ++r) {
        const int row = rowC + r;
        if (row < M) {
          if constexpr (DOT2) dot2out[row] = s2[r] + a2b[0];
          if constexpr (DOT1) dot1out[row] = s1[r] + a1b[0];
        }
      }
    }
  }
}

// ---------------- two-level counting sort of edges by destination bin ----------------
__device__ inline int edge_bin(int e, const int* r0, const int* r1, const int* r2) {
  if (e < CNE) return r0[e];
  if (e < 2 * CNE) return CN0 + r1[e - CNE];
  return 2 * CN0 + r2[e - 2 * CNE];
}
__device__ inline void edge_get(int e, const int* r0, const int* c0, const int* r1,
                                const int* c1, const int* r2, const int* c2,
                                int& bin, int& col) {
  if (e < CNE) { bin = r0[e]; col = c0[e]; }
  else if (e < 2 * CNE) { bin = CN0 + r1[e - CNE]; col = c1[e - CNE]; }
  else { bin = 2 * CN0 + r2[e - 2 * CNE]; col = c2[e - 2 * CNE]; }
}

__global__ __launch_bounds__(256) void coarse_hist_kernel(
    const int* __restrict__ r0, const int* __restrict__ r1, const int* __restrict__ r2,
    int* __restrict__ blockhist) {
  __shared__ int lh[NB];
  const int t = threadIdx.x;
  for (int i = t; i < NB; i += 256) lh[i] = 0;
  __syncthreads();
  const int e0 = blockIdx.x * CHUNK;
  for (int i = t; i < CHUNK; i += 256) {
    int e = e0 + i;
    if (e < TOT_E) atomicAdd(&lh[edge_bin(e, r0, r1, r2) >> 9], 1);
  }
  __syncthreads();
  for (int i = t; i < NB; i += 256) blockhist[(size_t)i * G + blockIdx.x] = lh[i];
}

__global__ void scan1g_kernel(int* __restrict__ data, int* __restrict__ bsums, int n) {
  __shared__ int lds[256];
  int t = threadIdx.x;
  int idx0 = blockIdx.x * 1024 + t * 4;
  int v[4];
#pragma unroll
  for (int j = 0; j < 4; ++j) v[j] = (idx0 + j < n) ? data[idx0 + j] : 0;
  int tsum = v[0] + v[1] + v[2] + v[3];
  lds[t] = tsum;
  __syncthreads();
  for (int off = 1; off < 256; off <<= 1) {
    int x = (t >= off) ? lds[t - off] : 0;
    __syncthreads();
    lds[t] += x;
    __syncthreads();
  }
  int run = lds[t] - tsum;
  if (t == 255) bsums[blockIdx.x] = lds[255];
#pragma unroll
  for (int j = 0; j < 4; ++j) {
    if (idx0 + j < n) data[idx0 + j] = run;
    run += v[j];
  }
}

__global__ void scan2g_kernel(int* __restrict__ bsums, int nb) {
  __shared__ int lds[512];
  int t = threadIdx.x;
  int v = (t < nb) ? bsums[t] : 0;
  lds[t] = v;
  __syncthreads();
  for (int off = 1; off < 512; off <<= 1) {
    int x = (t >= off) ? lds[t - off] : 0;
    __syncthreads();
    lds[t] += x;
    __syncthreads();
  }
  if (t < nb) bsums[t] = lds[t] - v;
}

__global__ void scan3g_kernel(int* __restrict__ data, const int* __restrict__ bsums, int n) {
  int t = threadIdx.x;
  int idx0 = blockIdx.x * 1024 + t * 4;
  int off = bsums[blockIdx.x];
#pragma unroll
  for (int j = 0; j < 4; ++j)
    if (idx0 + j < n) data[idx0 + j] += off;
}

__global__ __launch_bounds__(256) void reorder_kernel(
    const int* __restrict__ r0, const int* __restrict__ c0,
    const int* __restrict__ r1, const int* __restrict__ c1,
    const int* __restrict__ r2, const int* __restrict__ c2,
    const int* __restrict__ blockscan, uint32* __restrict__ bbuf) {
  __shared__ int lbase[NB];
  const int t = threadIdx.x;
  for (int i = t; i < NB; i += 256) lbase[i] = blockscan[(size_t)i * G + blockIdx.x];
  __syncthreads();
  const int e0 = blockIdx.x * CHUNK;
  for (int i = t; i < CHUNK; i += 256) {
    int e = e0 + i;
    if (e >= TOT_E) break;
    int bin, col;
    edge_get(e, r0, c0, r1, c1, r2, c2, bin, col);
    int pos = atomicAdd(&lbase[bin >> 9], 1);
    bbuf[pos] = ((uint32)(bin & 511) << 18) | (uint32)col;
  }
}

// P4: per-bucket LDS counting sort; fuses attention computation:
// output word = (att_q14 << 18) | col, att_q14 = round-to-nearest 14-bit of sigmoid.
__global__ __launch_bounds__(256) void finalize_kernel(
    const int* __restrict__ blockscan, const uint32* __restrict__ bbuf,
    const float* __restrict__ a1_0, const float* __restrict__ a2all,
    uint32* __restrict__ scols, int* __restrict__ rs) {
  __shared__ int lh[512];
  __shared__ int sc[256];
  const int t = threadIdx.x;
  const int b = blockIdx.x;
  const int binbase = b << 9;
  const int gs = blockscan[(size_t)b * G];
  const int ge = (b == NB - 1) ? TOT_E : blockscan[(size_t)(b + 1) * G];
  const int cnt = ge - gs;

  lh[2 * t] = 0;
  lh[2 * t + 1] = 0;
  __syncthreads();
  for (int i = t; i < cnt; i += 256) atomicAdd(&lh[bbuf[gs + i] >> 18], 1);
  __syncthreads();
  int v0 = lh[2 * t], v1 = lh[2 * t + 1];
  int tsum = v0 + v1;
  sc[t] = tsum;
  __syncthreads();
  for (int off = 1; off < 256; off <<= 1) {
    int x = (t >= off) ? sc[t - off] : 0;
    __syncthreads();
    sc[t] += x;
    __syncthreads();
  }
  int ex = sc[t] - tsum;
  lh[2 * t] = ex;
  lh[2 * t + 1] = ex + v0;
  int nb_here = NBINS - binbase;
  if (2 * t < nb_here) rs[binbase + 2 * t] = gs + ex;
  if (2 * t + 1 < nb_here) rs[binbase + 2 * t + 1] = gs + ex + v0;
  if (b == NB - 1 && t == 255) rs[NBINS] = TOT_E;
  __syncthreads();
  for (int i = t; i < cnt; i += 256) {
    uint32 p = bbuf[gs + i];
    int bl = (int)(p >> 18);
    int col = (int)(p & 0x3FFFFu);
    int gbin = binbase + bl;
    int a = (gbin >= 2 * CN0) ? 2 : ((gbin >= CN0) ? 1 : 0);
    int row = gbin - a * CN0;
    int aoff = (a == 0) ? 0 : ((a == 1) ? CN0 : CN0 + CN1);
    float z = a1_0[row] + a2all[aoff + col];
    float att = 1.0f / (1.0f + __expf(-z));
    int q = (int)(att * 16384.f);
    if (q > 16383) q = 16383;
    int pos = atomicAdd(&lh[bl], 1);
    scols[gs + pos] = ((uint32)q << 18) | (uint32)col;
  }
}

// ---------------- attention aggregation: one wave per (adjacency,row), unroll-4 -----
__global__ void agg_kernel_all(const int* __restrict__ rs, const uint32* __restrict__ scols,
                               const ushort16* __restrict__ h0,
                               const ushort16* __restrict__ h1,
                               const ushort16* __restrict__ h2,
                               ushort16* __restrict__ agg0, ushort16* __restrict__ agg1,
                               ushort16* __restrict__ agg2) {
  int w = (blockIdx.x * blockDim.x + threadIdx.x) >> 6;
  if (w >= NBINS) return;
  int lane = threadIdx.x & 63;
  int a = (w >= 2 * CN0) ? 2 : ((w >= CN0) ? 1 : 0);
  const ushort16* __restrict__ xj = (a == 0) ? h0 : ((a == 1) ? h1 : h2);
  ushort16* __restrict__ out = (a == 0) ? agg0 : ((a == 1) ? agg1 : agg2);
  int row = w - a * CN0;
  int s = rs[w], e = rs[w + 1];
  float ax = 0.f, ay = 0.f;
  const size_t loff = (size_t)lane * 2;
  int p = s;
  constexpr float SC = 1.0f / 16384.f;
  for (; p + 4 <= e; p += 4) {
    uint32 k0 = scols[p], k1 = scols[p + 1], k2 = scols[p + 2], k3 = scols[p + 3];
    float2 v0 = load2(xj, (size_t)(k0 & 0x3FFFFu) * CD + loff);
    float2 v1 = load2(xj, (size_t)(k1 & 0x3FFFFu) * CD + loff);
    float2 v2 = load2(xj, (size_t)(k2 & 0x3FFFFu) * CD + loff);
    float2 v3 = load2(xj, (size_t)(k3 & 0x3FFFFu) * CD + loff);
    float t0 = ((float)(k0 >> 18) + 0.5f) * SC;
    float t1 = ((float)(k1 >> 18) + 0.5f) * SC;
    float t2 = ((float)(k2 >> 18) + 0.5f) * SC;
    float t3 = ((float)(k3 >> 18) + 0.5f) * SC;
    ax = fmaf(t0, v0.x, ax); ay = fmaf(t0, v0.y, ay);
    ax = fmaf(t1, v1.x, ax); ay = fmaf(t1, v1.y, ay);
    ax = fmaf(t2, v2.x, ax); ay = fmaf(t2, v2.y, ay);
    ax = fmaf(t3, v3.x, ax); ay = fmaf(t3, v3.y, ay);
  }
  for (; p < e; ++p) {
    uint32 k = scols[p];
    float2 v = load2(xj, (size_t)(k & 0x3FFFFu) * CD + loff);
    float tt = ((float)(k >> 18) + 0.5f) * SC;
    ax = fmaf(tt, v.x, ax); ay = fmaf(tt, v.y, ay);
  }
  *(uint32*)(out + (size_t)row * CD + loff) = pack2(ax, ay);
}

// ---------------- launch ----------------
extern "C" void kernel_launch(void* const* d_in, const int* in_sizes, int n_in,
                              void* d_out, int out_size, void* d_ws, size_t ws_size,
                              hipStream_t stream) {
  const float* x0 = (const float*)d_in[0];
  const float* x1 = (const float*)d_in[1];
  const float* x2 = (const float*)d_in[2];
  const float* W1 = (const float*)d_in[3];
  const float* b1 = (const float*)d_in[4];
  const float* a1_w = (const float*)d_in[5];
  const float* a1_b = (const float*)d_in[6];
  const float* a2_w = (const float*)d_in[7];
  const float* a2_b = (const float*)d_in[8];
  const float* Wagg = (const float*)d_in[9];
  const float* bagg = (const float*)d_in[10];
  const int* adj0_r = (const int*)d_in[11];
  const int* adj0_c = (const int*)d_in[12];
  const int* adj1_r = (const int*)d_in[13];
  const int* adj1_c = (const int*)d_in[14];
  const int* adj2_r = (const int*)d_in[15];
  const int* adj2_c = (const int*)d_in[16];
  float* out = (float*)d_out;

  if (ws_size < OFF_END) return;  // tripwire

  char* ws = (char*)d_ws;
  ushort16* h0b    = (ushort16*)(ws + OFF_H0B);
  ushort16* h1b    = (ushort16*)(ws + OFF_H1B);
  ushort16* h2b    = (ushort16*)(ws + OFF_H2B);
  ushort16* agg1b  = (ushort16*)(ws + OFF_AG1);
  ushort16* agg2b  = (ushort16*)(ws + OFF_AG2);
  float*    a1_0   = (float*)(ws + OFF_A1);
  float*    a2all  = (float*)(ws + OFF_A2);
  int*      rs     = (int*)(ws + OFF_RS);
  int*      bh     = (int*)(ws + OFF_BH);
  uint32*   scols  = (uint32*)(ws + OFF_SCL);
  int*      bsums  = (int*)(ws + OFF_BS);
  uint32*   bbuf   = (uint32*)(ws + OFF_BB);     // live only during sort
  ushort16* agg0b  = (ushort16*)(ws + OFF_BB);   // overlays bbuf after finalize

  // 1) lin1: h = relu(x @ W1 + b1) -> bf16, with fused a1/a2 row-dots
  gemm_mfma<1, true, true, true, float, ushort16><<<(CN0 + 63) / 64, 256, 0, stream>>>(
      x0, x0, x0, x0, W1, b1, h0b, CN0, a1_w, a2_w, a1_b, a2_b, a1_0, a2all);
  gemm_mfma<1, true, false, true, float, ushort16><<<(CN1 + 63) / 64, 256, 0, stream>>>(
      x1, x1, x1, x1, W1, b1, h1b, CN1, a1_w, a2_w, a1_b, a2_b, a1_0, a2all + CN0);
  gemm_mfma<1, true, false, true, float, ushort16><<<(CN2 + 63) / 64, 256, 0, stream>>>(
      x2, x2, x2, x2, W1, b1, h2b, CN2, a1_w, a2_w, a1_b, a2_b, a1_0, a2all + CN0 + CN1);

  // 2) two-level counting sort; finalize fuses attention into packed scols
  coarse_hist_kernel<<<G, 256, 0, stream>>>(adj0_r, adj1_r, adj2_r, bh);
  scan1g_kernel<<<CSCAN_BLOCKS, 256, 0, stream>>>(bh, bsums, NBG);
  scan2g_kernel<<<1, 512, 0, stream>>>(bsums, CSCAN_BLOCKS);
  scan3g_kernel<<<CSCAN_BLOCKS, 256, 0, stream>>>(bh, bsums, NBG);
  reorder_kernel<<<G, 256, 0, stream>>>(adj0_r, adj0_c, adj1_r, adj1_c,
                                        adj2_r, adj2_c, bh, bbuf);
  finalize_kernel<<<NB, 256, 0, stream>>>(bh, bbuf, a1_0, a2all, scols, rs);

  // 3) aggregation, all 3 adjacencies in one dispatch (agg0b overlays dead bbuf)
  agg_kernel_all<<<(NBINS * 64 + 255) / 256, 256, 0, stream>>>(
      rs, scols, h0b, h1b, h2b, agg0b, agg1b, agg2b);

  // 4) out = [h0 | agg0 | agg1 | agg2] @ Wagg + bagg  (single K=512 MFMA GEMM)
  gemm_mfma<4, false, false, false, ushort16, float><<<(CN0 + 63) / 64, 256, 0, stream>>>(
      h0b, agg0b, agg1b, agg2b, Wagg, bagg, out, CN0,
      a1_w, a2_w, a1_b, a2_b, nullptr, nullptr);
}